// Round 5
// baseline (536.631 us; speedup 1.0000x reference)
//
#include <hip/hip_runtime.h>
#include <hip/hip_bf16.h>

#define NE 32
#define TOPK 4
#define HID 2048
#define INTER 768
#define NT 2048
#define MAXTILE 64

typedef float f32x4 __attribute__((ext_vector_type(4)));
typedef float f32x2 __attribute__((ext_vector_type(2)));
typedef unsigned int u32x4 __attribute__((ext_vector_type(4)));
typedef unsigned int u32x2 __attribute__((ext_vector_type(2)));
typedef short short8 __attribute__((ext_vector_type(8)));
typedef __bf16 bf16x8 __attribute__((ext_vector_type(8)));

__device__ inline unsigned short f2bf(float f) {
  unsigned u = __builtin_bit_cast(unsigned, f);
  u += 0x7fffu + ((u >> 16) & 1u);
  return (unsigned short)(u >> 16);
}
__device__ inline unsigned pack2(unsigned short a, unsigned short b) {
  return (unsigned)a | ((unsigned)b << 16);
}
__device__ inline f32x4 mfma_bf16(short8 a, short8 b, f32x4 c) {
  return __builtin_amdgcn_mfma_f32_16x16x32_bf16(
      __builtin_bit_cast(bf16x8, a), __builtin_bit_cast(bf16x8, b), c, 0, 0, 0);
}
__device__ inline void gload16(const void* g, void* l) {
  __builtin_amdgcn_global_load_lds(
      (const __attribute__((address_space(1))) void*)g,
      (__attribute__((address_space(3))) void*)l, 16, 0, 0);
}
// tile -> (expert, m0, base, ne); uniform across block
__device__ inline bool locate(const int* __restrict__ counts, int tile, int& e,
                              int& m0, int& base, int& ne) {
  int tl = tile;
  base = 0;
  for (e = 0; e < NE; ++e) {
    const int c = counts[e];
    const int nt = (c + 255) >> 8;
    if (tl < nt) {
      m0 = tl << 8;
      ne = c;
      return true;
    }
    tl -= nt;
    base += c;
  }
  return false;
}

// ---------------- router: 1 wave per token (+ fused X->bf16 row convert) ----------------
__global__ __launch_bounds__(64) void k_router(const float* __restrict__ X,
                                               const float* __restrict__ Wg,
                                               int* __restrict__ expert_of,
                                               float* __restrict__ weight_of,
                                               int* __restrict__ counts,
                                               unsigned short* __restrict__ Xb) {
  const int n = blockIdx.x;
  const int lane = threadIdx.x;
  const float* x = X + (size_t)n * HID;
  float acc[NE];
#pragma unroll
  for (int e = 0; e < NE; ++e) acc[e] = 0.f;
  for (int h = lane; h < HID; h += 64) {
    const float xv = x[h];
    const f32x4* wr = (const f32x4*)(Wg + (size_t)h * NE);
#pragma unroll
    for (int q = 0; q < NE / 4; ++q) {
      f32x4 w4 = wr[q];
      acc[q * 4 + 0] += xv * w4[0];
      acc[q * 4 + 1] += xv * w4[1];
      acc[q * 4 + 2] += xv * w4[2];
      acc[q * 4 + 3] += xv * w4[3];
    }
  }
  // fused bf16 convert of this row (L1-hot)
  const f32x4* x4 = (const f32x4*)x;
  u32x2* xb2 = (u32x2*)(Xb + (size_t)n * HID);
#pragma unroll
  for (int it = 0; it < HID / 4 / 64; ++it) {
    const int q = it * 64 + lane;
    f32x4 v = x4[q];
    u32x2 t = {pack2(f2bf(v[0]), f2bf(v[1])), pack2(f2bf(v[2]), f2bf(v[3]))};
    xb2[q] = t;
  }
#pragma unroll
  for (int off = 32; off >= 1; off >>= 1) {
#pragma unroll
    for (int e = 0; e < NE; ++e) acc[e] += __shfl_xor(acc[e], off, 64);
  }
  if (lane == 0) {
    float m = acc[0];
#pragma unroll
    for (int e = 1; e < NE; ++e) m = fmaxf(m, acc[e]);
    unsigned used = 0;
    int idx[TOPK];
    float wv[TOPK];
    float wsum = 0.f;
    for (int k = 0; k < TOPK; ++k) {
      int best = 0;
      float bv = -1e30f;
      for (int e = 0; e < NE; ++e) {
        if (!((used >> e) & 1u) && acc[e] > bv) { bv = acc[e]; best = e; }
      }
      used |= 1u << best;
      float w = expf(bv - m);
      idx[k] = best;
      wv[k] = w;
      wsum += w;
    }
    const float inv = 1.f / wsum;
    for (int k = 0; k < TOPK; ++k) {
      expert_of[n * TOPK + k] = idx[k];
      weight_of[n * TOPK + k] = wv[k] * inv;
      atomicAdd(&counts[idx[k]], 1);
    }
  }
}

// ---------------- deterministic stable scatter (1 wave per expert) ----------------
__global__ __launch_bounds__(64) void k_scatter(const int* __restrict__ expert_of,
                                                const float* __restrict__ weight_of,
                                                const int* __restrict__ counts,
                                                int* __restrict__ slot_token,
                                                float* __restrict__ slot_w) {
  const int e = blockIdx.x;
  const int lane = threadIdx.x;
  int cnt = 0;
  for (int i = 0; i < NE; ++i) cnt += (i < e) ? counts[i] : 0;
  for (int a0 = 0; a0 < NT * TOPK; a0 += 64) {
    const int a = a0 + lane;
    const bool m = (expert_of[a] == e);
    const unsigned long long bal = __ballot(m);
    if (m) {
      const int pos = cnt + __popcll(bal & ((1ull << lane) - 1ull));
      slot_token[pos] = a >> 2;
      slot_w[pos] = weight_of[a];
    }
    cnt += __popcll(bal);
  }
}

// ---------------- GEMM1: X[sel] @ Wgu -> silu(g)*u*w -> Y (bf16) ----------------
// M=256, N=64(gate)+64(up), BK=64, 512 threads (8 waves, 4m x 2n), double-buffered.
__global__ __launch_bounds__(512) void k_gemm1(const unsigned short* __restrict__ Xb,
                                               const float* __restrict__ Wgu,
                                               const int* __restrict__ slot_token,
                                               const float* __restrict__ slot_w,
                                               const int* __restrict__ counts,
                                               unsigned short* __restrict__ Y) {
  int e, m0, base, ne;
  if (!locate(counts, blockIdx.x, e, m0, base, ne)) return;
  const int n0 = blockIdx.y * 64;
  const int tid = threadIdx.x;
  const int lane = tid & 63, w = tid >> 6;
  const int wm = w >> 1, wn = w & 1;
  const int fr = lane & 15, fo = lane >> 4;
  const int lr = lane >> 3, lk = lane & 7;

  __shared__ __attribute__((aligned(16))) unsigned short As[2][256 * 64];  // 64 KB
  __shared__ __attribute__((aligned(16))) unsigned short Bg[2][64 * 64];   // 16 KB
  __shared__ __attribute__((aligned(16))) unsigned short Bu[2][64 * 64];   // 16 KB

  f32x4 accg[4][2], accu[4][2];
#pragma unroll
  for (int i = 0; i < 4; ++i)
#pragma unroll
    for (int j = 0; j < 2; ++j) {
      f32x4 z = {0.f, 0.f, 0.f, 0.f};
      accg[i][j] = z;
      accu[i][j] = z;
    }

  const unsigned short* asrc[4];
#pragma unroll
  for (int i = 0; i < 4; ++i) {
    const int ra = (w * 4 + i) * 8 + lr;
    const int tok = slot_token[base + min(m0 + ra, ne - 1)];
    asrc[i] = Xb + (size_t)tok * HID + ((lk ^ (ra & 7)) << 3);
  }

  const int np = tid & 31, kg = (tid >> 5) & 7, rg = tid >> 8;
  const float* bsrc = Wgu + (size_t)e * HID * (2 * INTER) +
                      (size_t)(kg * 8) * (2 * INTER) + rg * INTER + n0 + 2 * np;
  const int n_a = 2 * np, n_b = 2 * np + 1;
  const int wofa = n_a * 64 + ((kg ^ (n_a & 7)) << 3);
  const int wofb = n_b * 64 + ((kg ^ (n_b & 7)) << 3);

  auto stage_a = [&](int t, int b) {
#pragma unroll
    for (int i = 0; i < 4; ++i) gload16(asrc[i] + t * 64, &As[b][(w * 4 + i) * 512]);
  };
  auto load_b = [&](int t, f32x2* bv) {
    const float* bp = bsrc + (size_t)(t * 64) * (2 * INTER);
#pragma unroll
    for (int j = 0; j < 8; ++j) bv[j] = *(const f32x2*)(bp + (size_t)j * (2 * INTER));
  };
  auto pack_write = [&](const f32x2* bv, int b) {
    u32x4 ta = {pack2(f2bf(bv[0][0]), f2bf(bv[1][0])), pack2(f2bf(bv[2][0]), f2bf(bv[3][0])),
                pack2(f2bf(bv[4][0]), f2bf(bv[5][0])), pack2(f2bf(bv[6][0]), f2bf(bv[7][0]))};
    u32x4 tb = {pack2(f2bf(bv[0][1]), f2bf(bv[1][1])), pack2(f2bf(bv[2][1]), f2bf(bv[3][1])),
                pack2(f2bf(bv[4][1]), f2bf(bv[5][1])), pack2(f2bf(bv[6][1]), f2bf(bv[7][1]))};
    unsigned short* Bd = rg ? Bu[b] : Bg[b];
    *(u32x4*)&Bd[wofa] = ta;
    *(u32x4*)&Bd[wofb] = tb;
  };
  auto do_mfma = [&](int b) {
#pragma unroll
    for (int ks = 0; ks < 2; ++ks) {
      const int c = ks * 4 + fo;
      short8 a[4], bg[2], bu[2];
#pragma unroll
      for (int mi = 0; mi < 4; ++mi) {
        const int row = wm * 64 + mi * 16 + fr;
        a[mi] = *(const short8*)&As[b][row * 64 + ((c ^ (row & 7)) << 3)];
      }
#pragma unroll
      for (int ni = 0; ni < 2; ++ni) {
        const int row = wn * 32 + ni * 16 + fr;
        const int off = row * 64 + ((c ^ (row & 7)) << 3);
        bg[ni] = *(const short8*)&Bg[b][off];
        bu[ni] = *(const short8*)&Bu[b][off];
      }
#pragma unroll
      for (int mi = 0; mi < 4; ++mi)
#pragma unroll
        for (int ni = 0; ni < 2; ++ni) {
          accg[mi][ni] = mfma_bf16(a[mi], bg[ni], accg[mi][ni]);
          accu[mi][ni] = mfma_bf16(a[mi], bu[ni], accu[mi][ni]);
        }
    }
  };

  const int NS = HID / 64;
  {
    f32x2 bv[8];
    stage_a(0, 0);
    load_b(0, bv);
    pack_write(bv, 0);
  }
  __syncthreads();
#pragma unroll 2
  for (int t = 0; t < NS; ++t) {
    const int cur = t & 1, nxt = cur ^ 1;
    f32x2 bv[8];
    const bool more = (t + 1 < NS);
    if (more) {
      stage_a(t + 1, nxt);
      load_b(t + 1, bv);
    }
    __builtin_amdgcn_sched_barrier(0);
    do_mfma(cur);
    if (more) pack_write(bv, nxt);
    __syncthreads();
  }

#pragma unroll
  for (int mi = 0; mi < 4; ++mi) {
#pragma unroll
    for (int j = 0; j < 4; ++j) {
      const int gm = m0 + wm * 64 + mi * 16 + fo * 4 + j;
      if (gm < ne) {
        const float wgt = slot_w[base + gm];
        unsigned short* yp = Y + (size_t)(base + gm) * INTER + n0 + wn * 32;
#pragma unroll
        for (int ni = 0; ni < 2; ++ni) {
          const float g = accg[mi][ni][j];
          const float u = accu[mi][ni][j];
          const float yv = (g / (1.0f + __expf(-g))) * u * wgt;
          yp[ni * 16 + fr] = f2bf(yv);
        }
      }
    }
  }
}

// ---------------- GEMM2: Y @ Wd -> atomic scatter into out ----------------
// M=256, N=128, BK=64, K=INTER, 512 threads (8 waves, 4m x 2n), double-buffered.
__global__ __launch_bounds__(512) void k_gemm2(const unsigned short* __restrict__ Y,
                                               const float* __restrict__ Wd,
                                               const int* __restrict__ slot_token,
                                               const int* __restrict__ counts,
                                               float* __restrict__ out) {
  int e, m0, base, ne;
  if (!locate(counts, blockIdx.x, e, m0, base, ne)) return;
  const int n0 = blockIdx.y * 128;
  const int tid = threadIdx.x;
  const int lane = tid & 63, w = tid >> 6;
  const int wm = w >> 1, wn = w & 1;
  const int fr = lane & 15, fo = lane >> 4;
  const int lr = lane >> 3, lk = lane & 7;

  __shared__ __attribute__((aligned(16))) unsigned short As[2][256 * 64];  // 64 KB
  __shared__ __attribute__((aligned(16))) unsigned short Bs[2][128 * 64];  // 32 KB

  f32x4 acc[4][4];
#pragma unroll
  for (int i = 0; i < 4; ++i)
#pragma unroll
    for (int j = 0; j < 4; ++j) {
      f32x4 z = {0.f, 0.f, 0.f, 0.f};
      acc[i][j] = z;
    }

  const unsigned short* asrc[4];
#pragma unroll
  for (int i = 0; i < 4; ++i) {
    const int ra = (w * 4 + i) * 8 + lr;
    const int grow = base + min(m0 + ra, ne - 1);
    asrc[i] = Y + (size_t)grow * INTER + ((lk ^ (ra & 7)) << 3);
  }

  const int np = tid & 63, kg = tid >> 6;
  const float* bsrc = Wd + (size_t)e * INTER * HID + (size_t)(kg * 8) * HID + n0 + 2 * np;
  const int n_a = 2 * np, n_b = 2 * np + 1;
  const int wofa = n_a * 64 + ((kg ^ (n_a & 7)) << 3);
  const int wofb = n_b * 64 + ((kg ^ (n_b & 7)) << 3);

  auto stage_a = [&](int t, int b) {
#pragma unroll
    for (int i = 0; i < 4; ++i) gload16(asrc[i] + t * 64, &As[b][(w * 4 + i) * 512]);
  };
  auto load_b = [&](int t, f32x2* bv) {
    const float* bp = bsrc + (size_t)(t * 64) * HID;
#pragma unroll
    for (int j = 0; j < 8; ++j) bv[j] = *(const f32x2*)(bp + (size_t)j * HID);
  };
  auto pack_write = [&](const f32x2* bv, int b) {
    u32x4 ta = {pack2(f2bf(bv[0][0]), f2bf(bv[1][0])), pack2(f2bf(bv[2][0]), f2bf(bv[3][0])),
                pack2(f2bf(bv[4][0]), f2bf(bv[5][0])), pack2(f2bf(bv[6][0]), f2bf(bv[7][0]))};
    u32x4 tb = {pack2(f2bf(bv[0][1]), f2bf(bv[1][1])), pack2(f2bf(bv[2][1]), f2bf(bv[3][1])),
                pack2(f2bf(bv[4][1]), f2bf(bv[5][1])), pack2(f2bf(bv[6][1]), f2bf(bv[7][1]))};
    *(u32x4*)&Bs[b][wofa] = ta;
    *(u32x4*)&Bs[b][wofb] = tb;
  };
  auto do_mfma = [&](int b) {
#pragma unroll
    for (int ks = 0; ks < 2; ++ks) {
      const int c = ks * 4 + fo;
      short8 a[4], bb[4];
#pragma unroll
      for (int mi = 0; mi < 4; ++mi) {
        const int row = wm * 64 + mi * 16 + fr;
        a[mi] = *(const short8*)&As[b][row * 64 + ((c ^ (row & 7)) << 3)];
      }
#pragma unroll
      for (int ni = 0; ni < 4; ++ni) {
        const int row = wn * 64 + ni * 16 + fr;
        bb[ni] = *(const short8*)&Bs[b][row * 64 + ((c ^ (row & 7)) << 3)];
      }
#pragma unroll
      for (int mi = 0; mi < 4; ++mi)
#pragma unroll
        for (int ni = 0; ni < 4; ++ni) acc[mi][ni] = mfma_bf16(a[mi], bb[ni], acc[mi][ni]);
    }
  };

  const int NS = INTER / 64;
  {
    f32x2 bv[8];
    stage_a(0, 0);
    load_b(0, bv);
    pack_write(bv, 0);
  }
  __syncthreads();
#pragma unroll 2
  for (int t = 0; t < NS; ++t) {
    const int cur = t & 1, nxt = cur ^ 1;
    f32x2 bv[8];
    const bool more = (t + 1 < NS);
    if (more) {
      stage_a(t + 1, nxt);
      load_b(t + 1, bv);
    }
    __builtin_amdgcn_sched_barrier(0);
    do_mfma(cur);
    if (more) pack_write(bv, nxt);
    __syncthreads();
  }

#pragma unroll
  for (int mi = 0; mi < 4; ++mi) {
#pragma unroll
    for (int j = 0; j < 4; ++j) {
      const int gm = m0 + wm * 64 + mi * 16 + fo * 4 + j;
      if (gm < ne) {
        const int tok = slot_token[base + gm];
        float* op = out + (size_t)tok * HID + n0 + wn * 64;
#pragma unroll
        for (int ni = 0; ni < 4; ++ni) atomicAdd(&op[ni * 16 + fr], acc[mi][ni][j]);
      }
    }
  }
}

extern "C" void kernel_launch(void* const* d_in, const int* in_sizes, int n_in,
                              void* d_out, int out_size, void* d_ws, size_t ws_size,
                              hipStream_t stream) {
  (void)in_sizes; (void)n_in; (void)ws_size;
  const float* X = (const float*)d_in[0];
  const float* Wg = (const float*)d_in[1];
  const float* Wgu = (const float*)d_in[2];
  const float* Wd = (const float*)d_in[3];
  float* out = (float*)d_out;

  char* ws = (char*)d_ws;
  int* counts = (int*)(ws + 0);
  int* expert_of = (int*)(ws + 2048);
  float* weight_of = (float*)(ws + 2048 + 32768);
  int* slot_token = (int*)(ws + 2048 + 2 * 32768);
  float* slot_w = (float*)(ws + 2048 + 3 * 32768);
  unsigned short* Xb = (unsigned short*)(ws + 133120);   // 8 MB
  unsigned short* Yb = (unsigned short*)(ws + 8521728);  // 12.6 MB

  hipMemsetAsync(counts, 0, 128, stream);
  hipMemsetAsync(d_out, 0, (size_t)out_size * sizeof(float), stream);

  k_router<<<NT, 64, 0, stream>>>(X, Wg, expert_of, weight_of, counts, Xb);
  k_scatter<<<NE, 64, 0, stream>>>(expert_of, weight_of, counts, slot_token, slot_w);
  k_gemm1<<<dim3(MAXTILE, INTER / 64), 512, 0, stream>>>(Xb, Wgu, slot_token, slot_w,
                                                         counts, Yb);
  k_gemm2<<<dim3(MAXTILE, HID / 128), 512, 0, stream>>>(Yb, Wd, slot_token, counts, out);
}

// Round 6
// 508.241 us; speedup vs baseline: 1.0559x; 1.0559x over previous
//
#include <hip/hip_runtime.h>
#include <hip/hip_bf16.h>

#define NE 32
#define TOPK 4
#define HID 2048
#define INTER 768
#define NT 2048
#define MAXTILE 96

typedef float f32x4 __attribute__((ext_vector_type(4)));
typedef float f32x2 __attribute__((ext_vector_type(2)));
typedef unsigned int u32x4 __attribute__((ext_vector_type(4)));
typedef unsigned int u32x2 __attribute__((ext_vector_type(2)));
typedef short short8 __attribute__((ext_vector_type(8)));
typedef __bf16 bf16x8 __attribute__((ext_vector_type(8)));

__device__ inline unsigned short f2bf(float f) {
  unsigned u = __builtin_bit_cast(unsigned, f);
  u += 0x7fffu + ((u >> 16) & 1u);
  return (unsigned short)(u >> 16);
}
__device__ inline unsigned pack2(unsigned short a, unsigned short b) {
  return (unsigned)a | ((unsigned)b << 16);
}
__device__ inline f32x4 mfma_bf16(short8 a, short8 b, f32x4 c) {
  return __builtin_amdgcn_mfma_f32_16x16x32_bf16(
      __builtin_bit_cast(bf16x8, a), __builtin_bit_cast(bf16x8, b), c, 0, 0, 0);
}
__device__ inline void gload16(const void* g, void* l) {
  __builtin_amdgcn_global_load_lds(
      (const __attribute__((address_space(1))) void*)g,
      (__attribute__((address_space(3))) void*)l, 16, 0, 0);
}
// tile (128-row) -> (expert, m0, base, ne); uniform across block
__device__ inline bool locate(const int* __restrict__ counts, int tile, int& e,
                              int& m0, int& base, int& ne) {
  int tl = tile;
  base = 0;
  for (e = 0; e < NE; ++e) {
    const int c = counts[e];
    const int nt = (c + 127) >> 7;
    if (tl < nt) {
      m0 = tl << 7;
      ne = c;
      return true;
    }
    tl -= nt;
    base += c;
  }
  return false;
}

// ---------------- router: 1 wave per token (+ fused X->bf16 row convert) ----------------
__global__ __launch_bounds__(64) void k_router(const float* __restrict__ X,
                                               const float* __restrict__ Wg,
                                               int* __restrict__ expert_of,
                                               float* __restrict__ weight_of,
                                               int* __restrict__ counts,
                                               unsigned short* __restrict__ Xb) {
  const int n = blockIdx.x;
  const int lane = threadIdx.x;
  const float* x = X + (size_t)n * HID;
  float acc[NE];
#pragma unroll
  for (int e = 0; e < NE; ++e) acc[e] = 0.f;
  for (int h = lane; h < HID; h += 64) {
    const float xv = x[h];
    const f32x4* wr = (const f32x4*)(Wg + (size_t)h * NE);
#pragma unroll
    for (int q = 0; q < NE / 4; ++q) {
      f32x4 w4 = wr[q];
      acc[q * 4 + 0] += xv * w4[0];
      acc[q * 4 + 1] += xv * w4[1];
      acc[q * 4 + 2] += xv * w4[2];
      acc[q * 4 + 3] += xv * w4[3];
    }
  }
  const f32x4* x4 = (const f32x4*)x;
  u32x2* xb2 = (u32x2*)(Xb + (size_t)n * HID);
#pragma unroll
  for (int it = 0; it < HID / 4 / 64; ++it) {
    const int q = it * 64 + lane;
    f32x4 v = x4[q];
    u32x2 t = {pack2(f2bf(v[0]), f2bf(v[1])), pack2(f2bf(v[2]), f2bf(v[3]))};
    xb2[q] = t;
  }
#pragma unroll
  for (int off = 32; off >= 1; off >>= 1) {
#pragma unroll
    for (int e = 0; e < NE; ++e) acc[e] += __shfl_xor(acc[e], off, 64);
  }
  if (lane == 0) {
    float m = acc[0];
#pragma unroll
    for (int e = 1; e < NE; ++e) m = fmaxf(m, acc[e]);
    unsigned used = 0;
    int idx[TOPK];
    float wv[TOPK];
    float wsum = 0.f;
    for (int k = 0; k < TOPK; ++k) {
      int best = 0;
      float bv = -1e30f;
      for (int e = 0; e < NE; ++e) {
        if (!((used >> e) & 1u) && acc[e] > bv) { bv = acc[e]; best = e; }
      }
      used |= 1u << best;
      float w = expf(bv - m);
      idx[k] = best;
      wv[k] = w;
      wsum += w;
    }
    const float inv = 1.f / wsum;
    for (int k = 0; k < TOPK; ++k) {
      expert_of[n * TOPK + k] = idx[k];
      weight_of[n * TOPK + k] = wv[k] * inv;
      atomicAdd(&counts[idx[k]], 1);
    }
  }
}

// ---------------- deterministic stable scatter (1 wave per expert) ----------------
__global__ __launch_bounds__(64) void k_scatter(const int* __restrict__ expert_of,
                                                const float* __restrict__ weight_of,
                                                const int* __restrict__ counts,
                                                int* __restrict__ slot_token,
                                                float* __restrict__ slot_w) {
  const int e = blockIdx.x;
  const int lane = threadIdx.x;
  int cnt = 0;
  for (int i = 0; i < NE; ++i) cnt += (i < e) ? counts[i] : 0;
  for (int a0 = 0; a0 < NT * TOPK; a0 += 64) {
    const int a = a0 + lane;
    const bool m = (expert_of[a] == e);
    const unsigned long long bal = __ballot(m);
    if (m) {
      const int pos = cnt + __popcll(bal & ((1ull << lane) - 1ull));
      slot_token[pos] = a >> 2;
      slot_w[pos] = weight_of[a];
    }
    cnt += __popcll(bal);
  }
}

// ---------------- GEMM1: X[sel] @ Wgu -> silu(g)*u*w -> Y (bf16) ----------------
// M=128, N=64g+64u, BK=64, 512 thr (8 waves 4m x 2n), A LDS-dbuf, B 2-deep reg
// prefetch, raw s_barrier + counted vmcnt (loads span barriers).
__global__ __launch_bounds__(512, 4) void k_gemm1(
    const unsigned short* __restrict__ Xb, const float* __restrict__ Wgu,
    const int* __restrict__ slot_token, const float* __restrict__ slot_w,
    const int* __restrict__ counts, unsigned short* __restrict__ Y) {
  int e, m0, base, ne;
  if (!locate(counts, blockIdx.x, e, m0, base, ne)) return;
  const int n0 = blockIdx.y * 64;
  const int tid = threadIdx.x;
  const int lane = tid & 63, w = tid >> 6;
  const int wm = w >> 1, wn = w & 1;
  const int fr = lane & 15, fo = lane >> 4;
  const int lr = lane >> 3, lk = lane & 7;

  __shared__ __attribute__((aligned(16))) unsigned short As[2][128 * 64];  // 32 KB
  __shared__ __attribute__((aligned(16))) unsigned short Bg[2][64 * 64];   // 16 KB
  __shared__ __attribute__((aligned(16))) unsigned short Bu[2][64 * 64];   // 16 KB

  f32x4 accg[2][2], accu[2][2];
#pragma unroll
  for (int i = 0; i < 2; ++i)
#pragma unroll
    for (int j = 0; j < 2; ++j) {
      f32x4 z = {0.f, 0.f, 0.f, 0.f};
      accg[i][j] = z;
      accu[i][j] = z;
    }

  const unsigned short* asrc[2];
#pragma unroll
  for (int i = 0; i < 2; ++i) {
    const int ra = (w * 2 + i) * 8 + lr;  // 0..127
    const int tok = slot_token[base + min(m0 + ra, ne - 1)];
    asrc[i] = Xb + (size_t)tok * HID + ((lk ^ (ra & 7)) << 3);
  }

  const int np = tid & 31, kg = (tid >> 5) & 7, rg = tid >> 8;
  const float* bsrc = Wgu + (size_t)e * HID * (2 * INTER) +
                      (size_t)(kg * 8) * (2 * INTER) + rg * INTER + n0 + 2 * np;
  const int n_a = 2 * np, n_b = 2 * np + 1;
  const int wofa = n_a * 64 + ((kg ^ (n_a & 7)) << 3);
  const int wofb = n_b * 64 + ((kg ^ (n_b & 7)) << 3);

  auto stage_a = [&](int t, int b) {
#pragma unroll
    for (int i = 0; i < 2; ++i) gload16(asrc[i] + t * 64, &As[b][(w * 2 + i) * 512]);
  };
  auto load_b = [&](int t, f32x2* bv) {
    const float* bp = bsrc + (size_t)(t * 64) * (2 * INTER);
#pragma unroll
    for (int j = 0; j < 8; ++j) bv[j] = *(const f32x2*)(bp + (size_t)j * (2 * INTER));
  };
  auto pack_write = [&](const f32x2* bv, int b) {
    u32x4 ta = {pack2(f2bf(bv[0][0]), f2bf(bv[1][0])), pack2(f2bf(bv[2][0]), f2bf(bv[3][0])),
                pack2(f2bf(bv[4][0]), f2bf(bv[5][0])), pack2(f2bf(bv[6][0]), f2bf(bv[7][0]))};
    u32x4 tb = {pack2(f2bf(bv[0][1]), f2bf(bv[1][1])), pack2(f2bf(bv[2][1]), f2bf(bv[3][1])),
                pack2(f2bf(bv[4][1]), f2bf(bv[5][1])), pack2(f2bf(bv[6][1]), f2bf(bv[7][1]))};
    unsigned short* Bd = rg ? Bu[b] : Bg[b];
    *(u32x4*)&Bd[wofa] = ta;
    *(u32x4*)&Bd[wofb] = tb;
  };
  auto do_mfma = [&](int b) {
#pragma unroll
    for (int ks = 0; ks < 2; ++ks) {
      const int c = ks * 4 + fo;
      short8 a[2], bg[2], bu[2];
#pragma unroll
      for (int mi = 0; mi < 2; ++mi) {
        const int row = wm * 32 + mi * 16 + fr;
        a[mi] = *(const short8*)&As[b][row * 64 + ((c ^ (row & 7)) << 3)];
      }
#pragma unroll
      for (int ni = 0; ni < 2; ++ni) {
        const int row = wn * 32 + ni * 16 + fr;
        const int off = row * 64 + ((c ^ (row & 7)) << 3);
        bg[ni] = *(const short8*)&Bg[b][off];
        bu[ni] = *(const short8*)&Bu[b][off];
      }
#pragma unroll
      for (int mi = 0; mi < 2; ++mi)
#pragma unroll
        for (int ni = 0; ni < 2; ++ni) {
          accg[mi][ni] = mfma_bf16(a[mi], bg[ni], accg[mi][ni]);
          accu[mi][ni] = mfma_bf16(a[mi], bu[ni], accu[mi][ni]);
        }
    }
  };

  const int NS = HID / 64;  // 32
  f32x2 bv[2][8];
  // prologue: A0 staged, B0+B1 loaded, B0 written
  stage_a(0, 0);
  load_b(0, bv[0]);
  load_b(1, bv[1]);
  pack_write(bv[0], 0);  // compiler auto-waits bv[0]
  asm volatile("s_waitcnt lgkmcnt(0)" ::: "memory");
  __builtin_amdgcn_s_barrier();

#pragma unroll 2
  for (int t = 0; t < NS - 2; ++t) {
    const int cur = t & 1, nxt = cur ^ 1;
    stage_a(t + 1, nxt);       // 2 vmem
    load_b(t + 2, bv[cur]);    // 8 vmem (slot of consumed tile t)
    // outstanding <= 20 (A-t 2, B-t+1 8, A-t+1 2, B-t+2 8); need A-t done:
    asm volatile("s_waitcnt vmcnt(18)" ::: "memory");
    do_mfma(cur);
    pack_write(bv[nxt], nxt);  // auto-wait B-t+1 (vmcnt(10)) -> 10 ops cross barrier
    asm volatile("s_waitcnt lgkmcnt(0)" ::: "memory");
    __builtin_amdgcn_s_barrier();
  }
  {  // t = NS-2: no more B loads
    const int t = NS - 2, cur = t & 1, nxt = cur ^ 1;
    stage_a(t + 1, nxt);
    asm volatile("s_waitcnt vmcnt(10)" ::: "memory");  // A-t done (12 outstanding max)
    do_mfma(cur);
    pack_write(bv[nxt], nxt);
    __syncthreads();  // full drain (covers A-(NS-1))
  }
  do_mfma((NS - 1) & 1);

#pragma unroll
  for (int mi = 0; mi < 2; ++mi) {
#pragma unroll
    for (int j = 0; j < 4; ++j) {
      const int gm = m0 + wm * 32 + mi * 16 + fo * 4 + j;
      if (gm < ne) {
        const float wgt = slot_w[base + gm];
        unsigned short* yp = Y + (size_t)(base + gm) * INTER + n0 + wn * 32;
#pragma unroll
        for (int ni = 0; ni < 2; ++ni) {
          const float g = accg[mi][ni][j];
          const float u = accu[mi][ni][j];
          const float yv = (g / (1.0f + __expf(-g))) * u * wgt;
          yp[ni * 16 + fr] = f2bf(yv);
        }
      }
    }
  }
}

// ---------------- GEMM2: Y @ Wd -> atomic scatter into out ----------------
// M=128, N=128, BK=64, K=INTER, same pipeline as gemm1.
__global__ __launch_bounds__(512, 4) void k_gemm2(
    const unsigned short* __restrict__ Y, const float* __restrict__ Wd,
    const int* __restrict__ slot_token, const int* __restrict__ counts,
    float* __restrict__ out) {
  int e, m0, base, ne;
  if (!locate(counts, blockIdx.x, e, m0, base, ne)) return;
  const int n0 = blockIdx.y * 128;
  const int tid = threadIdx.x;
  const int lane = tid & 63, w = tid >> 6;
  const int wm = w >> 1, wn = w & 1;
  const int fr = lane & 15, fo = lane >> 4;
  const int lr = lane >> 3, lk = lane & 7;

  __shared__ __attribute__((aligned(16))) unsigned short As[2][128 * 64];  // 32 KB
  __shared__ __attribute__((aligned(16))) unsigned short Bs[2][128 * 64];  // 32 KB

  f32x4 acc[2][4];
#pragma unroll
  for (int i = 0; i < 2; ++i)
#pragma unroll
    for (int j = 0; j < 4; ++j) {
      f32x4 z = {0.f, 0.f, 0.f, 0.f};
      acc[i][j] = z;
    }

  const unsigned short* asrc[2];
#pragma unroll
  for (int i = 0; i < 2; ++i) {
    const int ra = (w * 2 + i) * 8 + lr;
    const int grow = base + min(m0 + ra, ne - 1);
    asrc[i] = Y + (size_t)grow * INTER + ((lk ^ (ra & 7)) << 3);
  }

  const int np = tid & 63, kg = tid >> 6;
  const float* bsrc = Wd + (size_t)e * INTER * HID + (size_t)(kg * 8) * HID + n0 + 2 * np;
  const int n_a = 2 * np, n_b = 2 * np + 1;
  const int wofa = n_a * 64 + ((kg ^ (n_a & 7)) << 3);
  const int wofb = n_b * 64 + ((kg ^ (n_b & 7)) << 3);

  auto stage_a = [&](int t, int b) {
#pragma unroll
    for (int i = 0; i < 2; ++i) gload16(asrc[i] + t * 64, &As[b][(w * 2 + i) * 512]);
  };
  auto load_b = [&](int t, f32x2* bv) {
    const float* bp = bsrc + (size_t)(t * 64) * HID;
#pragma unroll
    for (int j = 0; j < 8; ++j) bv[j] = *(const f32x2*)(bp + (size_t)j * HID);
  };
  auto pack_write = [&](const f32x2* bv, int b) {
    u32x4 ta = {pack2(f2bf(bv[0][0]), f2bf(bv[1][0])), pack2(f2bf(bv[2][0]), f2bf(bv[3][0])),
                pack2(f2bf(bv[4][0]), f2bf(bv[5][0])), pack2(f2bf(bv[6][0]), f2bf(bv[7][0]))};
    u32x4 tb = {pack2(f2bf(bv[0][1]), f2bf(bv[1][1])), pack2(f2bf(bv[2][1]), f2bf(bv[3][1])),
                pack2(f2bf(bv[4][1]), f2bf(bv[5][1])), pack2(f2bf(bv[6][1]), f2bf(bv[7][1]))};
    *(u32x4*)&Bs[b][wofa] = ta;
    *(u32x4*)&Bs[b][wofb] = tb;
  };
  auto do_mfma = [&](int b) {
#pragma unroll
    for (int ks = 0; ks < 2; ++ks) {
      const int c = ks * 4 + fo;
      short8 a[2], bb[4];
#pragma unroll
      for (int mi = 0; mi < 2; ++mi) {
        const int row = wm * 32 + mi * 16 + fr;
        a[mi] = *(const short8*)&As[b][row * 64 + ((c ^ (row & 7)) << 3)];
      }
#pragma unroll
      for (int ni = 0; ni < 4; ++ni) {
        const int row = wn * 64 + ni * 16 + fr;
        bb[ni] = *(const short8*)&Bs[b][row * 64 + ((c ^ (row & 7)) << 3)];
      }
#pragma unroll
      for (int mi = 0; mi < 2; ++mi)
#pragma unroll
        for (int ni = 0; ni < 4; ++ni) acc[mi][ni] = mfma_bf16(a[mi], bb[ni], acc[mi][ni]);
    }
  };

  const int NS = INTER / 64;  // 12
  f32x2 bv[2][8];
  stage_a(0, 0);
  load_b(0, bv[0]);
  load_b(1, bv[1]);
  pack_write(bv[0], 0);
  asm volatile("s_waitcnt lgkmcnt(0)" ::: "memory");
  __builtin_amdgcn_s_barrier();

#pragma unroll 2
  for (int t = 0; t < NS - 2; ++t) {
    const int cur = t & 1, nxt = cur ^ 1;
    stage_a(t + 1, nxt);
    load_b(t + 2, bv[cur]);
    asm volatile("s_waitcnt vmcnt(18)" ::: "memory");
    do_mfma(cur);
    pack_write(bv[nxt], nxt);
    asm volatile("s_waitcnt lgkmcnt(0)" ::: "memory");
    __builtin_amdgcn_s_barrier();
  }
  {
    const int t = NS - 2, cur = t & 1, nxt = cur ^ 1;
    stage_a(t + 1, nxt);
    asm volatile("s_waitcnt vmcnt(10)" ::: "memory");
    do_mfma(cur);
    pack_write(bv[nxt], nxt);
    __syncthreads();
  }
  do_mfma((NS - 1) & 1);

#pragma unroll
  for (int mi = 0; mi < 2; ++mi) {
#pragma unroll
    for (int j = 0; j < 4; ++j) {
      const int gm = m0 + wm * 32 + mi * 16 + fo * 4 + j;
      if (gm < ne) {
        const int tok = slot_token[base + gm];
        float* op = out + (size_t)tok * HID + n0 + wn * 64;
#pragma unroll
        for (int ni = 0; ni < 4; ++ni) atomicAdd(&op[ni * 16 + fr], acc[mi][ni][j]);
      }
    }
  }
}

extern "C" void kernel_launch(void* const* d_in, const int* in_sizes, int n_in,
                              void* d_out, int out_size, void* d_ws, size_t ws_size,
                              hipStream_t stream) {
  (void)in_sizes; (void)n_in; (void)ws_size;
  const float* X = (const float*)d_in[0];
  const float* Wg = (const float*)d_in[1];
  const float* Wgu = (const float*)d_in[2];
  const float* Wd = (const float*)d_in[3];
  float* out = (float*)d_out;

  char* ws = (char*)d_ws;
  int* counts = (int*)(ws + 0);
  int* expert_of = (int*)(ws + 2048);
  float* weight_of = (float*)(ws + 2048 + 32768);
  int* slot_token = (int*)(ws + 2048 + 2 * 32768);
  float* slot_w = (float*)(ws + 2048 + 3 * 32768);
  unsigned short* Xb = (unsigned short*)(ws + 133120);   // 8 MB
  unsigned short* Yb = (unsigned short*)(ws + 8521728);  // 12.6 MB

  hipMemsetAsync(counts, 0, 128, stream);
  hipMemsetAsync(d_out, 0, (size_t)out_size * sizeof(float), stream);

  k_router<<<NT, 64, 0, stream>>>(X, Wg, expert_of, weight_of, counts, Xb);
  k_scatter<<<NE, 64, 0, stream>>>(expert_of, weight_of, counts, slot_token, slot_w);
  k_gemm1<<<dim3(MAXTILE, INTER / 64), 512, 0, stream>>>(Xb, Wgu, slot_token, slot_w,
                                                         counts, Yb);
  k_gemm2<<<dim3(MAXTILE, HID / 128), 512, 0, stream>>>(Yb, Wd, slot_token, counts, out);
}